// Round 1
// baseline (246.039 us; speedup 1.0000x reference)
//
#include <hip/hip_runtime.h>
#include <hip/hip_bf16.h>

// Problem constants
#define NB 256     // batch
#define NC 273     // C_IN (= K)
#define ND 273     // C_OUT (= M)
#define NT 360     // T (= N)
#define NSUB 128

// Tiling
#define BM 96      // D rows per block (3 tiles: 288 >= 273)
#define BN 128     // T cols per block (3 tiles: 384 >= 360)
#define BK 32
#define LDK 40     // padded LDS K-stride (elements): 80 B rows, 16B-aligned b128 reads

typedef __bf16 bf16_t;
typedef bf16_t bf16x4 __attribute__((ext_vector_type(4)));
typedef bf16_t bf16x8 __attribute__((ext_vector_type(8)));
typedef float  f32x4  __attribute__((ext_vector_type(4)));

__global__ __launch_bounds__(256) void subject_gemm(
    const float* __restrict__ x,        // [B, C, T]
    const int*   __restrict__ subjects, // [B]
    const float* __restrict__ w,        // [S, C, D]
    float*       __restrict__ out)      // [B, D, T]
{
    const int bid = blockIdx.x;
    const int b   = bid / 9;
    const int r   = bid % 9;
    const int dt  = r / 3;
    const int tt  = r % 3;
    const int d0  = dt * BM;
    const int t0  = tt * BN;
    const int s   = subjects[b];

    const float* __restrict__ xb = x + (size_t)b * NC * NT;
    const float* __restrict__ ws = w + (size_t)s * NC * ND;

    __shared__ __align__(16) bf16_t As[BM * LDK]; // [d][k]
    __shared__ __align__(16) bf16_t Bs[BN * LDK]; // [t][k]

    const int tid   = threadIdx.x;
    const int lane  = tid & 63;
    const int wid   = tid >> 6;   // 0..3
    const int wm    = wid >> 1;   // wave row (D): 0..1, 48 rows each
    const int wn    = wid & 1;    // wave col (T): 0..1, 64 cols each
    const int l16   = lane & 15;
    const int khalf = lane >> 4;  // 0..3 -> k-offset group of 8

    // Precompute staging coordinates (loop-invariant)
    // A: q = tid + 256*j (j=0..2): d = q % 96, kq = q / 96 (0..7)
    int dA[3], kqA[3];
#pragma unroll
    for (int j = 0; j < 3; ++j) {
        int q = tid + 256 * j;
        dA[j]  = q % BM;
        kqA[j] = q / BM;
    }
    // B: q = tid + 256*j (j=0..3): t = q & 127, kq = q >> 7 (0..7)

    f32x4 acc[3][4];
#pragma unroll
    for (int m = 0; m < 3; ++m)
#pragma unroll
        for (int n = 0; n < 4; ++n)
            acc[m][n] = (f32x4){0.f, 0.f, 0.f, 0.f};

    for (int kk = 0; kk < NC; kk += BK) {
        // ---- stage A tile: As[d][k] = w[s, kk+k, d0+d] (bf16) ----
#pragma unroll
        for (int j = 0; j < 3; ++j) {
            const int d  = dA[j];
            const int kq = kqA[j];
            const int gd = d0 + d;
            const bool okd = (gd < ND);
            bf16x4 v;
#pragma unroll
            for (int u = 0; u < 4; ++u) {
                const int c = kk + kq * 4 + u;
                float f = (okd && c < NC) ? ws[(size_t)c * ND + gd] : 0.f;
                v[u] = (bf16_t)f;
            }
            *(bf16x4*)&As[d * LDK + kq * 4] = v;
        }
        // ---- stage B tile: Bs[t][k] = x[b, kk+k, t0+t] (bf16) ----
#pragma unroll
        for (int j = 0; j < 4; ++j) {
            const int q  = tid + 256 * j;
            const int t  = q & (BN - 1);
            const int kq = q >> 7;
            const int gt = t0 + t;
            const bool okt = (gt < NT);
            bf16x4 v;
#pragma unroll
            for (int u = 0; u < 4; ++u) {
                const int c = kk + kq * 4 + u;
                float f = (okt && c < NC) ? xb[(size_t)c * NT + gt] : 0.f;
                v[u] = (bf16_t)f;
            }
            *(bf16x4*)&Bs[t * LDK + kq * 4] = v;
        }
        __syncthreads();

        // ---- fragments + MFMA ----
        bf16x8 af[3], bfr[4];
#pragma unroll
        for (int m = 0; m < 3; ++m)
            af[m] = *(const bf16x8*)&As[(wm * 48 + m * 16 + l16) * LDK + khalf * 8];
#pragma unroll
        for (int n = 0; n < 4; ++n)
            bfr[n] = *(const bf16x8*)&Bs[(wn * 64 + n * 16 + l16) * LDK + khalf * 8];

#pragma unroll
        for (int m = 0; m < 3; ++m)
#pragma unroll
            for (int n = 0; n < 4; ++n)
                acc[m][n] = __builtin_amdgcn_mfma_f32_16x16x32_bf16(
                    af[m], bfr[n], acc[m][n], 0, 0, 0);

        __syncthreads();
    }

    // ---- epilogue: C/D layout col=lane&15 (t), row=(lane>>4)*4+reg (d) ----
    float* __restrict__ ob = out + (size_t)b * ND * NT;
#pragma unroll
    for (int m = 0; m < 3; ++m) {
#pragma unroll
        for (int n = 0; n < 4; ++n) {
#pragma unroll
            for (int rg = 0; rg < 4; ++rg) {
                const int d = d0 + wm * 48 + m * 16 + khalf * 4 + rg;
                const int t = t0 + wn * 64 + n * 16 + l16;
                if (d < ND && t < NT)
                    ob[(size_t)d * NT + t] = acc[m][n][rg];
            }
        }
    }
}

extern "C" void kernel_launch(void* const* d_in, const int* in_sizes, int n_in,
                              void* d_out, int out_size, void* d_ws, size_t ws_size,
                              hipStream_t stream) {
    const float* x        = (const float*)d_in[0];
    const int*   subjects = (const int*)d_in[1];
    const float* w        = (const float*)d_in[2];
    float*       out      = (float*)d_out;

    const int nblocks = NB * 3 * 3; // b-major: 9 tiles per sample
    subject_gemm<<<nblocks, 256, 0, stream>>>(x, subjects, w, out);
}

// Round 2
// 85.245 us; speedup vs baseline: 2.8863x; 2.8863x over previous
//
#include <hip/hip_runtime.h>
#include <hip/hip_bf16.h>

// Problem constants
#define NBATCH 256
#define NC 273     // C_IN (K)
#define ND 273     // C_OUT (M)
#define NT 360     // T (N)

// Tiling: one block = full D (288 padded) x 120 t-columns, K-steps of 32
#define BM 288
#define BN 128     // LDS cols (120 valid + 8 pad)
#define BNV 120
#define BK 32
#define LDK 40     // padded LDS row stride (elements) -> 80 B rows
#define KITERS 9   // ceil(273/32)

typedef __bf16 bf16_t;
typedef bf16_t bf16x4 __attribute__((ext_vector_type(4)));
typedef bf16_t bf16x8 __attribute__((ext_vector_type(8)));
typedef float  f32x4  __attribute__((ext_vector_type(4)));

__global__ __launch_bounds__(256, 2) void subject_gemm(
    const float* __restrict__ x,        // [B, C, T]
    const int*   __restrict__ subjects, // [B]
    const float* __restrict__ w,        // [S, C, D]
    float*       __restrict__ out)      // [B, D, T]
{
    // 768 blocks = 8 XCDs x 96 slots; keep a sample's 3 t-tiles on one XCD.
    const int raw  = blockIdx.x;
    const int xcd  = raw & 7;
    const int slot = raw >> 3;          // 0..95
    const int b    = xcd * 32 + slot / 3;
    const int tt   = slot % 3;
    const int t0   = tt * BNV;
    const int s    = subjects[b];

    const float* __restrict__ xb = x + (size_t)b * NC * NT;
    const float* __restrict__ ws = w + (size_t)s * NC * ND;

    __shared__ __align__(16) bf16_t As[BM * LDK]; // [d][k]
    __shared__ __align__(16) bf16_t Bs[BN * LDK]; // [t][k]

    const int tid   = threadIdx.x;
    const int lane  = tid & 63;
    const int wid   = tid >> 6;   // 0..3
    const int wm    = wid >> 1;   // D half: 144 rows
    const int wn    = wid & 1;    // T half: 64 cols
    const int l16   = lane & 15;
    const int khalf = lane >> 4;  // 0..3

    // ---- staging coordinates (loop-invariant) ----
    // A: 2304 cells = (kq 0..7) x (d 0..287); i = tid + 256*j, d = i%288, kq = i/288
    int offA[9], gA[9];
#pragma unroll
    for (int j = 0; j < 9; ++j) {
        const int i  = tid + 256 * j;
        const int d  = i % BM;
        const int kq = i / BM;
        offA[j] = d * LDK + kq * 4;
        gA[j]   = kq * 4 * ND + d;          // + kk*ND + u*ND at load time
    }
    // B: 1024 cells = (kq 0..7) x (t 0..127); t = i&127, kq = i>>7
    int offB[4], gB[4];
#pragma unroll
    for (int j = 0; j < 4; ++j) {
        const int i  = tid + 256 * j;
        const int t  = i & (BN - 1);
        const int kq = i >> 7;
        const int tc = (t < BNV) ? t : (BNV - 1);   // clamp pad cols (garbage ok, masked at store)
        offB[j] = t * LDK + kq * 4;
        gB[j]   = kq * 4 * NT + t0 + tc;
    }

    float ra[9][4], rb[4][4];

    // Full (unmasked) loads: kk in [0,224] -> c <= 255 < 273, idx always in-bounds.
    auto loadA_full = [&](int kk) {
        const int base = kk * ND;
#pragma unroll
        for (int j = 0; j < 9; ++j)
#pragma unroll
            for (int u = 0; u < 4; ++u)
                ra[j][u] = ws[base + gA[j] + u * ND];
    };
    auto loadB_full = [&](int kk) {
        const int base = kk * NT;
#pragma unroll
        for (int j = 0; j < 4; ++j)
#pragma unroll
            for (int u = 0; u < 4; ++u)
                rb[j][u] = xb[base + gB[j] + u * NT];
    };
    // Tail (kk=256): c in [256,288) -> mask c>=273; A must be ZERO there (kills B tail garbage).
    auto loadA_tail = [&]() {
#pragma unroll
        for (int j = 0; j < 9; ++j) {
            const int i  = tid + 256 * j;
            const int d  = i % BM;
            const int kq = i / BM;
#pragma unroll
            for (int u = 0; u < 4; ++u) {
                const int c = 256 + kq * 4 + u;
                const bool ok = (c < NC) && (d < ND);
                ra[j][u] = ok ? ws[c * ND + d] : 0.f;
            }
        }
    };
    auto loadB_tail = [&]() {
#pragma unroll
        for (int j = 0; j < 4; ++j) {
            const int i  = tid + 256 * j;
            const int t  = i & (BN - 1);
            const int kq = i >> 7;
            const int col = t0 + ((t < BNV) ? t : (BNV - 1));
#pragma unroll
            for (int u = 0; u < 4; ++u) {
                const int c  = 256 + kq * 4 + u;
                const int cc = (c < NC) ? c : (NC - 1);  // clamp address; value harmless (A-side is 0)
                rb[j][u] = xb[cc * NT + col];
            }
        }
    };
    auto stage = [&]() {
#pragma unroll
        for (int j = 0; j < 9; ++j) {
            bf16x4 v;
#pragma unroll
            for (int u = 0; u < 4; ++u) v[u] = (bf16_t)ra[j][u];
            *(bf16x4*)&As[offA[j]] = v;
        }
#pragma unroll
        for (int j = 0; j < 4; ++j) {
            bf16x4 v;
#pragma unroll
            for (int u = 0; u < 4; ++u) v[u] = (bf16_t)rb[j][u];
            *(bf16x4*)&Bs[offB[j]] = v;
        }
    };

    f32x4 acc[9][4];
#pragma unroll
    for (int m = 0; m < 9; ++m)
#pragma unroll
        for (int n = 0; n < 4; ++n)
            acc[m][n] = (f32x4){0.f, 0.f, 0.f, 0.f};

    loadA_full(0);
    loadB_full(0);

#pragma unroll
    for (int it = 0; it < KITERS; ++it) {
        stage();                 // vmcnt wait happens here (loads issued one phase earlier)
        __syncthreads();

        // Issue next tile's global loads NOW so they fly under the MFMA phase (T14)
        if (it + 1 < KITERS - 1) {
            loadA_full((it + 1) * BK);
            loadB_full((it + 1) * BK);
        } else if (it + 1 == KITERS - 1) {
            loadA_tail();
            loadB_tail();
        }

        bf16x8 bfr[4];
#pragma unroll
        for (int n = 0; n < 4; ++n)
            bfr[n] = *(const bf16x8*)&Bs[(wn * 64 + n * 16 + l16) * LDK + khalf * 8];
#pragma unroll
        for (int m = 0; m < 9; ++m) {
            const bf16x8 af = *(const bf16x8*)&As[(wm * 144 + m * 16 + l16) * LDK + khalf * 8];
#pragma unroll
            for (int n = 0; n < 4; ++n)
                acc[m][n] = __builtin_amdgcn_mfma_f32_16x16x32_bf16(af, bfr[n], acc[m][n], 0, 0, 0);
        }
        __syncthreads();
    }

    // Epilogue: C/D layout col(t)=lane&15, row(d)=(lane>>4)*4+reg (verified in round 1)
    float* __restrict__ ob = out + (size_t)b * ND * NT;
#pragma unroll
    for (int m = 0; m < 9; ++m) {
#pragma unroll
        for (int n = 0; n < 4; ++n) {
            const int tc = wn * 64 + n * 16 + l16;
            const int gt = t0 + tc;
#pragma unroll
            for (int rg = 0; rg < 4; ++rg) {
                const int d = wm * 144 + m * 16 + khalf * 4 + rg;
                if (d < ND && tc < BNV)
                    ob[(size_t)d * NT + gt] = acc[m][n][rg];
            }
        }
    }
}

extern "C" void kernel_launch(void* const* d_in, const int* in_sizes, int n_in,
                              void* d_out, int out_size, void* d_ws, size_t ws_size,
                              hipStream_t stream) {
    const float* x        = (const float*)d_in[0];
    const int*   subjects = (const int*)d_in[1];
    const float* w        = (const float*)d_in[2];
    float*       out      = (float*)d_out;

    const int nblocks = NBATCH * 3; // 768 = 8 XCDs * 96
    subject_gemm<<<nblocks, 256, 0, stream>>>(x, subjects, w, out);
}

// Round 3
// 60.486 us; speedup vs baseline: 4.0677x; 1.4093x over previous
//
#include <hip/hip_runtime.h>
#include <hip/hip_bf16.h>

// Problem constants
#define NBATCH 256
#define NC 273     // C_IN (K)
#define ND 273     // C_OUT (M)
#define NT 360     // T (N)

// Tiling: one block = full D (288 padded) x 120 t-columns, K-steps of 32
#define THREADS 512
#define BM 288
#define BN 128     // LDS cols (120 valid + 8 pad)
#define BNV 120
#define BK 32
#define LDK 40     // padded LDS row stride (elements) -> 80 B rows, 16B-aligned b128
#define KITERS 9   // ceil(273/32)

typedef __bf16 bf16_t;
typedef bf16_t bf16x4 __attribute__((ext_vector_type(4)));
typedef bf16_t bf16x8 __attribute__((ext_vector_type(8)));
typedef float  f32x4  __attribute__((ext_vector_type(4)));

__global__ __launch_bounds__(THREADS, 1) void subject_gemm(
    const float* __restrict__ x,        // [B, C, T]
    const int*   __restrict__ subjects, // [B]
    const float* __restrict__ w,        // [S, C, D]
    float*       __restrict__ out)      // [B, D, T]
{
    // 768 blocks = 8 XCDs x 96 slots; keep a sample's 3 t-tiles on one XCD.
    const int raw  = blockIdx.x;
    const int xcd  = raw & 7;
    const int slot = raw >> 3;          // 0..95
    const int b    = xcd * 32 + slot / 3;
    const int tt   = slot % 3;
    const int t0   = tt * BNV;
    const int s    = subjects[b];

    const float* __restrict__ xb = x + (size_t)b * NC * NT;
    const float* __restrict__ ws = w + (size_t)s * NC * ND;

    __shared__ __align__(16) bf16_t As[BM * LDK]; // [d][k]
    __shared__ __align__(16) bf16_t Bs[BN * LDK]; // [t][k]

    const int tid   = threadIdx.x;
    const int lane  = tid & 63;
    const int wid   = tid >> 6;   // 0..7
    const int wm    = wid >> 2;   // D half: 144 rows
    const int wn    = wid & 3;    // T quarter: 32 cols
    const int l16   = lane & 15;
    const int khalf = lane >> 4;  // 0..3

    // ---- staging coordinates (loop-invariant) ----
    // A: 2304 bf16x4-cells = (d 0..287) x (kq 0..7); cell i = tid + 512*j
    //    j=0..3 full, j=4 only tid<256.
    int offA[5], gA[5];
#pragma unroll
    for (int j = 0; j < 5; ++j) {
        const int i  = tid + THREADS * j;   // < 2304 for valid ones
        const int ii = (i < 2304) ? i : 2303;
        const int d  = ii % BM;
        const int kq = ii / BM;
        offA[j] = d * LDK + kq * 4;
        gA[j]   = kq * 4 * ND + d;          // + kk*ND + u*ND at load time
    }
    // B: 1024 cells = (t 0..127) x (kq 0..7); i = tid + 512*j, j=0..1
    int offB[2], gB[2];
#pragma unroll
    for (int j = 0; j < 2; ++j) {
        const int i  = tid + THREADS * j;
        const int t  = i & (BN - 1);
        const int kq = i >> 7;
        const int tc = (t < BNV) ? t : (BNV - 1);   // clamp pad cols (garbage ok, masked at store)
        offB[j] = t * LDK + kq * 4;
        gB[j]   = kq * 4 * NT + t0 + tc;
    }
    const bool haveJ4 = (tid < 2304 - 4 * THREADS); // tid < 256

    float ra[5][4], rb[2][4];

    // Full (unmasked) loads: kk in [0,224] -> c <= 255 < 273; A d<=287 stays
    // inside W[s] since c*273+287 <= 255*273+287 < 273*273.
    auto loadA_full = [&](int kk) {
        const int base = kk * ND;
#pragma unroll
        for (int j = 0; j < 4; ++j)
#pragma unroll
            for (int u = 0; u < 4; ++u)
                ra[j][u] = ws[base + gA[j] + u * ND];
        if (haveJ4)
#pragma unroll
            for (int u = 0; u < 4; ++u)
                ra[4][u] = ws[base + gA[4] + u * ND];
    };
    auto loadB_full = [&](int kk) {
        const int base = kk * NT;
#pragma unroll
        for (int j = 0; j < 2; ++j)
#pragma unroll
            for (int u = 0; u < 4; ++u)
                rb[j][u] = xb[base + gB[j] + u * NT];
    };
    // Tail (kk=256): c in [256,288) -> zero A where c>=273 (kills B tail garbage).
    auto loadA_tail = [&]() {
#pragma unroll
        for (int j = 0; j < 5; ++j) {
            if (j == 4 && !haveJ4) break;
            const int i  = tid + THREADS * j;
            const int d  = i % BM;
            const int kq = i / BM;
#pragma unroll
            for (int u = 0; u < 4; ++u) {
                const int c = 256 + kq * 4 + u;
                const bool ok = (c < NC) && (d < ND);
                ra[j][u] = ok ? ws[c * ND + d] : 0.f;
            }
        }
    };
    auto loadB_tail = [&]() {
#pragma unroll
        for (int j = 0; j < 2; ++j) {
            const int i  = tid + THREADS * j;
            const int t  = i & (BN - 1);
            const int kq = i >> 7;
            const int col = t0 + ((t < BNV) ? t : (BNV - 1));
#pragma unroll
            for (int u = 0; u < 4; ++u) {
                const int c  = 256 + kq * 4 + u;
                const int cc = (c < NC) ? c : (NC - 1);  // clamp addr; value killed by A zeros
                rb[j][u] = xb[cc * NT + col];
            }
        }
    };
    auto stage = [&]() {
#pragma unroll
        for (int j = 0; j < 4; ++j) {
            bf16x4 v;
#pragma unroll
            for (int u = 0; u < 4; ++u) v[u] = (bf16_t)ra[j][u];
            *(bf16x4*)&As[offA[j]] = v;
        }
        if (haveJ4) {
            bf16x4 v;
#pragma unroll
            for (int u = 0; u < 4; ++u) v[u] = (bf16_t)ra[4][u];
            *(bf16x4*)&As[offA[4]] = v;
        }
#pragma unroll
        for (int j = 0; j < 2; ++j) {
            bf16x4 v;
#pragma unroll
            for (int u = 0; u < 4; ++u) v[u] = (bf16_t)rb[j][u];
            *(bf16x4*)&Bs[offB[j]] = v;
        }
    };

    f32x4 acc[9][2];
#pragma unroll
    for (int m = 0; m < 9; ++m)
#pragma unroll
        for (int n = 0; n < 2; ++n)
            acc[m][n] = (f32x4){0.f, 0.f, 0.f, 0.f};

    loadA_full(0);
    loadB_full(0);

#pragma unroll
    for (int it = 0; it < KITERS; ++it) {
        stage();                 // vmcnt wait here; loads were issued one phase earlier
        __syncthreads();

        // Issue next tile's global loads so they fly under ds_read + MFMA (T14)
        if (it + 1 < KITERS - 1) {
            loadA_full((it + 1) * BK);
            loadB_full((it + 1) * BK);
        } else if (it + 1 == KITERS - 1) {
            loadA_tail();
            loadB_tail();
        }

        bf16x8 bfr[2];
#pragma unroll
        for (int n = 0; n < 2; ++n)
            bfr[n] = *(const bf16x8*)&Bs[(wn * 32 + n * 16 + l16) * LDK + khalf * 8];
#pragma unroll
        for (int m = 0; m < 9; ++m) {
            const bf16x8 af = *(const bf16x8*)&As[(wm * 144 + m * 16 + l16) * LDK + khalf * 8];
#pragma unroll
            for (int n = 0; n < 2; ++n)
                acc[m][n] = __builtin_amdgcn_mfma_f32_16x16x32_bf16(af, bfr[n], acc[m][n], 0, 0, 0);
        }
        __syncthreads();
    }

    // Epilogue: C/D layout col(t)=lane&15, row(d)=(lane>>4)*4+reg (verified R1/R2)
    float* __restrict__ ob = out + (size_t)b * ND * NT;
#pragma unroll
    for (int m = 0; m < 9; ++m) {
#pragma unroll
        for (int n = 0; n < 2; ++n) {
            const int tc = wn * 32 + n * 16 + l16;
            const int gt = t0 + tc;
#pragma unroll
            for (int rg = 0; rg < 4; ++rg) {
                const int d = wm * 144 + m * 16 + khalf * 4 + rg;
                if (d < ND && tc < BNV)
                    ob[(size_t)d * NT + gt] = acc[m][n][rg];
            }
        }
    }
}

extern "C" void kernel_launch(void* const* d_in, const int* in_sizes, int n_in,
                              void* d_out, int out_size, void* d_ws, size_t ws_size,
                              hipStream_t stream) {
    const float* x        = (const float*)d_in[0];
    const int*   subjects = (const int*)d_in[1];
    const float* w        = (const float*)d_in[2];
    float*       out      = (float*)d_out;

    const int nblocks = NBATCH * 3; // 768 = 8 XCDs * 96
    subject_gemm<<<nblocks, THREADS, 0, stream>>>(x, subjects, w, out);
}

// Round 4
// 57.170 us; speedup vs baseline: 4.3036x; 1.0580x over previous
//
#include <hip/hip_runtime.h>
#include <hip/hip_bf16.h>

// Problem constants
#define NBATCH 256
#define NC 273     // C_IN (K)
#define ND 273     // C_OUT (M)
#define NT 360     // T (N)

// Tiling: one block = full D (288 padded) x 120 t-columns, K-steps of 32
#define THREADS 512
#define BM 288
#define BN 128     // LDS cols (120 valid + 8 pad)
#define BNV 120
#define BK 32
#define LDK 40     // padded LDS row stride (elements) -> 80 B rows, 16B-aligned b128
#define KITERS 9   // ceil(273/32); tiles 0..7 full, tile 8 = tail

typedef __bf16 bf16_t;
typedef bf16_t bf16x4 __attribute__((ext_vector_type(4)));
typedef bf16_t bf16x8 __attribute__((ext_vector_type(8)));
typedef float  f32x4  __attribute__((ext_vector_type(4)));

__global__ __launch_bounds__(THREADS, 2) void subject_gemm(
    const float* __restrict__ x,        // [B, C, T]
    const int*   __restrict__ subjects, // [B]
    const float* __restrict__ w,        // [S, C, D]
    float*       __restrict__ out)      // [B, D, T]
{
    // 768 blocks = 8 XCDs x 96 slots; keep a sample's 3 t-tiles on one XCD.
    const int raw  = blockIdx.x;
    const int xcd  = raw & 7;
    const int slot = raw >> 3;          // 0..95
    const int b    = xcd * 32 + slot / 3;
    const int tt   = slot % 3;
    const int t0   = tt * BNV;
    const int s    = subjects[b];

    const float* __restrict__ xb = x + (size_t)b * NC * NT;
    const float* __restrict__ ws = w + (size_t)s * NC * ND;

    // Double-buffered LDS: 2 x (288*40 + 128*40) bf16 = 66560 B (fits 160 KB pool)
    __shared__ __align__(16) bf16_t As[2][BM * LDK]; // [buf][d][k]
    __shared__ __align__(16) bf16_t Bs[2][BN * LDK]; // [buf][t][k]

    const int tid   = threadIdx.x;
    const int lane  = tid & 63;
    const int wid   = tid >> 6;   // 0..7
    const int wm    = wid >> 2;   // D half: 144 rows
    const int wn    = wid & 3;    // T quarter: 32 cols
    const int l16   = lane & 15;
    const int khalf = lane >> 4;  // 0..3

    // ---- staging coordinates (loop-invariant) ----
    // A: 2304 bf16x4-cells = (d 0..287) x (kq 0..7); cell i = tid + 512*j
    //    j=0..3 full, j=4 only tid<256.
    int offA[5], gA[5];
#pragma unroll
    for (int j = 0; j < 5; ++j) {
        const int i  = tid + THREADS * j;
        const int ii = (i < 2304) ? i : 2303;
        const int d  = ii % BM;
        const int kq = ii / BM;
        offA[j] = d * LDK + kq * 4;
        gA[j]   = kq * 4 * ND + d;          // + kk*ND + u*ND at load time
    }
    // B: 1024 cells = (t 0..127) x (kq 0..7); i = tid + 512*j, j=0..1
    int offB[2], gB[2];
#pragma unroll
    for (int j = 0; j < 2; ++j) {
        const int i  = tid + THREADS * j;
        const int t  = i & (BN - 1);
        const int kq = i >> 7;
        const int tc = (t < BNV) ? t : (BNV - 1);   // clamp pad cols (garbage ok, masked at store)
        offB[j] = t * LDK + kq * 4;
        gB[j]   = kq * 4 * NT + t0 + tc;
    }
    const bool haveJ4 = (tid < 2304 - 4 * THREADS); // tid < 256

    // Depth-2 register staging buffers (tile t lives in buf t&1)
    float ra[2][5][4], rb[2][2][4];

    // Full (unmasked) loads: kk <= 224 -> c <= 255 < 273; A d<=287 stays inside
    // W[s] since 255*273+287 < 273*273 (values masked at store).
    auto loadA = [&](float (&r)[5][4], int kk) {
        const int base = kk * ND;
#pragma unroll
        for (int j = 0; j < 4; ++j)
#pragma unroll
            for (int u = 0; u < 4; ++u)
                r[j][u] = ws[base + gA[j] + u * ND];
        if (haveJ4)
#pragma unroll
            for (int u = 0; u < 4; ++u)
                r[4][u] = ws[base + gA[4] + u * ND];
    };
    auto loadB = [&](float (&r)[2][4], int kk) {
        const int base = kk * NT;
#pragma unroll
        for (int j = 0; j < 2; ++j)
#pragma unroll
            for (int u = 0; u < 4; ++u)
                r[j][u] = xb[base + gB[j] + u * NT];
    };
    // Tail (kk=256): zero A where c>=273 or d>=273 (A zeros kill B tail garbage).
    auto loadA_tail = [&](float (&r)[5][4]) {
#pragma unroll
        for (int j = 0; j < 5; ++j) {
            if (j == 4 && !haveJ4) break;
            const int i  = tid + THREADS * j;
            const int d  = i % BM;
            const int kq = i / BM;
#pragma unroll
            for (int u = 0; u < 4; ++u) {
                const int c = 256 + kq * 4 + u;
                const bool ok = (c < NC) && (d < ND);
                r[j][u] = ok ? ws[c * ND + d] : 0.f;
            }
        }
    };
    auto loadB_tail = [&](float (&r)[2][4]) {
#pragma unroll
        for (int j = 0; j < 2; ++j) {
            const int i  = tid + THREADS * j;
            const int t  = i & (BN - 1);
            const int kq = i >> 7;
            const int col = t0 + ((t < BNV) ? t : (BNV - 1));
#pragma unroll
            for (int u = 0; u < 4; ++u) {
                const int c  = 256 + kq * 4 + u;
                const int cc = (c < NC) ? c : (NC - 1);  // clamp addr; value killed by A zeros
                r[j][u] = xb[cc * NT + col];
            }
        }
    };
    auto stage = [&](const float (&rA)[5][4], const float (&rB)[2][4],
                     bf16_t* __restrict__ dA, bf16_t* __restrict__ dB) {
#pragma unroll
        for (int j = 0; j < 4; ++j) {
            bf16x4 v;
#pragma unroll
            for (int u = 0; u < 4; ++u) v[u] = (bf16_t)rA[j][u];
            *(bf16x4*)&dA[offA[j]] = v;
        }
        if (haveJ4) {
            bf16x4 v;
#pragma unroll
            for (int u = 0; u < 4; ++u) v[u] = (bf16_t)rA[4][u];
            *(bf16x4*)&dA[offA[4]] = v;
        }
#pragma unroll
        for (int j = 0; j < 2; ++j) {
            bf16x4 v;
#pragma unroll
            for (int u = 0; u < 4; ++u) v[u] = (bf16_t)rB[j][u];
            *(bf16x4*)&dB[offB[j]] = v;
        }
    };

    f32x4 acc[9][2];
#pragma unroll
    for (int m = 0; m < 9; ++m)
#pragma unroll
        for (int n = 0; n < 2; ++n)
            acc[m][n] = (f32x4){0.f, 0.f, 0.f, 0.f};

    // ---- prologue: tiles 0 and 1 in flight; tile 0 staged ----
    loadA(ra[0], 0);      loadB(rb[0], 0);
    loadA(ra[1], BK);     loadB(rb[1], BK);
    stage(ra[0], rb[0], As[0], Bs[0]);
    __syncthreads();

#pragma unroll
    for (int it = 0; it < KITERS; ++it) {
        const int cur = it & 1;
        const bf16_t* __restrict__ Ac = As[cur];
        const bf16_t* __restrict__ Bc = Bs[cur];

        // 1) fragment ds_reads from current buffer (issued before any ds_write)
        bf16x8 af[9], bfr[2];
#pragma unroll
        for (int n = 0; n < 2; ++n)
            bfr[n] = *(const bf16x8*)&Bc[(wn * 32 + n * 16 + l16) * LDK + khalf * 8];
#pragma unroll
        for (int m = 0; m < 9; ++m)
            af[m] = *(const bf16x8*)&Ac[(wm * 144 + m * 16 + l16) * LDK + khalf * 8];

        // 2) issue global loads for tile it+2 (depth-2 prefetch, T4/T14)
        if (it + 2 <= KITERS - 2) {
            loadA(ra[cur], (it + 2) * BK);
            loadB(rb[cur], (it + 2) * BK);
        } else if (it + 2 == KITERS - 1) {
            loadA_tail(ra[cur]);
            loadB_tail(rb[cur]);
        }

        // 3) stage tile it+1 -> LDS[cur^1] (vmcnt waits on loads issued a full iter ago;
        //    ds_writes overlap this iter's MFMA reads, disjoint buffer)
        if (it + 1 < KITERS)
            stage(ra[cur ^ 1], rb[cur ^ 1], As[cur ^ 1], Bs[cur ^ 1]);

        // 4) MFMA
#pragma unroll
        for (int m = 0; m < 9; ++m)
#pragma unroll
            for (int n = 0; n < 2; ++n)
                acc[m][n] = __builtin_amdgcn_mfma_f32_16x16x32_bf16(af[m], bfr[n], acc[m][n], 0, 0, 0);

        __syncthreads();
    }

    // Epilogue: C/D layout col(t)=lane&15, row(d)=(lane>>4)*4+reg (verified R1-R3)
    float* __restrict__ ob = out + (size_t)b * ND * NT;
#pragma unroll
    for (int m = 0; m < 9; ++m) {
#pragma unroll
        for (int n = 0; n < 2; ++n) {
            const int tc = wn * 32 + n * 16 + l16;
            const int gt = t0 + tc;
#pragma unroll
            for (int rg = 0; rg < 4; ++rg) {
                const int d = wm * 144 + m * 16 + khalf * 4 + rg;
                if (d < ND && tc < BNV)
                    ob[(size_t)d * NT + gt] = acc[m][n][rg];
            }
        }
    }
}

extern "C" void kernel_launch(void* const* d_in, const int* in_sizes, int n_in,
                              void* d_out, int out_size, void* d_ws, size_t ws_size,
                              hipStream_t stream) {
    const float* x        = (const float*)d_in[0];
    const int*   subjects = (const int*)d_in[1];
    const float* w        = (const float*)d_in[2];
    float*       out      = (float*)d_out;

    const int nblocks = NBATCH * 3; // 768 = 8 XCDs * 96
    subject_gemm<<<nblocks, THREADS, 0, stream>>>(x, subjects, w, out);
}